// Round 14
// baseline (123.072 us; speedup 1.0000x reference)
//
#include <hip/hip_runtime.h>

// Cost volume, D=4: out[b,s,h,w] = mean_c feat1[b,c,h,w] * feat2[b,c,h,w+s-4]
// feat1/feat2: (8, 256, 96, 320) f32; out: (8, 9, 96, 320) f32.
// R14 = R13 single-kernel skeleton (r = channel sub-group, wave-contiguous
// rows, padded-LDS feat2 window, barrier-pinned prefetch) +
//  1) depth-2 register prefetch (4 KB/wave in flight; ds_write's vmcnt wait
//     satisfied 2 barriers earlier),
//  2) float4-only epilogue: quarter-threads gather per-plane sums from LDS
//     and emit dense dwordx4 stores (16 lanes x 16B = 256B/wave contiguous).
// gfx950 empirical rule (R1/R12/R13 vs R2/R5): per-lane dword global stores
// amplify HBM writes ~7x; only dense dwordx4 stores write exact bytes.
// R11 lesson: no depth>=3 prefetch (spills). R10: no fences/cross-block sync.

constexpr int B  = 8;
constexpr int C  = 256;
constexpr int H  = 96;
constexpr int W  = 320;
constexpr int NS = 9;              // 2*D+1 shifts
constexpr int QT = W / 4;          // 80 float4 per row
constexpr int NTH = QT * 4;        // 320 threads: tid = r*80 + q
constexpr int HW  = H * W;
constexpr int CH_STRIDE = 4 * HW;  // channel-group step (4 channels/iter)
constexpr int ITERS = C / 4;       // 64 iterations per thread
constexpr int PADW = W + 8;        // 4-float zero halo each side

__global__ __launch_bounds__(NTH, 3)
void cv_kernel(const float* __restrict__ f1,
               const float* __restrict__ f2,
               float* __restrict__ out) {
    __shared__ float bufA[4][PADW];   // feat2 rows, one per channel sub-group
    __shared__ float bufB[4][PADW];   // double buffer; 10.5 KB total

    const int tid = threadIdx.x;
    const int q   = tid % QT;         // float4 index within the row
    const int r   = tid / QT;         // channel sub-group (wave-contiguous)

    const int blk = blockIdx.x;       // 768 blocks = one per (b,h) row
    const int h   = blk % H;
    const int b   = blk / H;

    const size_t off = ((size_t)(b * C + r) * H + h) * (size_t)W + 4 * q;
    const float* p1 = f1 + off;
    const float* p2 = f2 + off;

    // Zero the halo pads once (covered by the first STEP's barrier).
    if (q == 0) {
#pragma unroll
        for (int k = 0; k < 4; ++k) { bufA[r][k] = 0.f; bufB[r][k] = 0.f; }
    }
    if (q == QT - 1) {
#pragma unroll
        for (int k = 0; k < 4; ++k) {
            bufA[r][4 + W + k] = 0.f; bufB[r][4 + W + k] = 0.f;
        }
    }

    float acc[4][NS];
#pragma unroll
    for (int j = 0; j < 4; ++j)
#pragma unroll
        for (int s = 0; s < NS; ++s) acc[j][s] = 0.0f;

    // Prologue: channels (group) 0 and 1 in flight (depth-2).
    float4 aP = *reinterpret_cast<const float4*>(p1);
    float4 rP = *reinterpret_cast<const float4*>(p2);
    float4 aN = *reinterpret_cast<const float4*>(p1 + (size_t)CH_STRIDE);
    float4 rN = *reinterpret_cast<const float4*>(p2 + (size_t)CH_STRIDE);
    int cnext = 2;   // next issue index; clamped at tail (dummy L1-hot reload)

    // One STEP per channel-iteration:
    //   ds_write current feat2 row (arrived 2 barriers ago -> no vmcnt stall)
    //   -> issue iter c+2's 2 loads -> lgkmcnt(0) + raw s_barrier (prefetch
    //   loads stay in flight across it) -> unconditional 12-float window
    //   from padded LDS (middle 4 from register) -> 36 FMAs -> rotate.
#define STEP(BUF)                                                          \
    {                                                                      \
        *reinterpret_cast<float4*>(&BUF[r][4 + 4 * q]) = rP;               \
        const float4 aL = *reinterpret_cast<const float4*>(                \
            p1 + (size_t)cnext * CH_STRIDE);                               \
        const float4 rL = *reinterpret_cast<const float4*>(                \
            p2 + (size_t)cnext * CH_STRIDE);                               \
        cnext = (cnext < ITERS - 1) ? cnext + 1 : cnext;                   \
        asm volatile("s_waitcnt lgkmcnt(0)" ::: "memory");                 \
        __builtin_amdgcn_s_barrier();                                      \
        asm volatile("" ::: "memory");                                     \
        const float4 x0 = *reinterpret_cast<const float4*>(&BUF[r][4 * q]);\
        const float4 x2 =                                                  \
            *reinterpret_cast<const float4*>(&BUF[r][4 * q + 8]);          \
        const float xw[12] = {x0.x, x0.y, x0.z, x0.w,                      \
                              rP.x, rP.y, rP.z, rP.w,                      \
                              x2.x, x2.y, x2.z, x2.w};                     \
        const float av[4] = {aP.x, aP.y, aP.z, aP.w};                      \
        _Pragma("unroll")                                                  \
        for (int j = 0; j < 4; ++j)                                        \
            _Pragma("unroll")                                              \
            for (int s = 0; s < NS; ++s)                                   \
                acc[j][s] = fmaf(av[j], xw[j + s], acc[j][s]);             \
        aP = aN; rP = rN; aN = aL; rN = rL;                                \
    }

#pragma unroll 1
    for (int c = 0; c < ITERS; c += 2) {
        STEP(bufA)
        STEP(bufB)
    }
#undef STEP

    // Epilogue: per s-plane LDS transpose; quarter-threads emit float4.
    // Stage: thread (r,q) writes its 4 w-values of plane s at bufA[r][4q].
    // Gather: threads with tid&3 == s&3 (16/wave) read the 4 sub-group rows
    // (b128, 2-way bank alias = free), sum, scale, and store ONE float4 ->
    // 16 lanes x 16B = 256B contiguous per wave (exact-write store pattern).
    const float scale = 1.0f / (float)C;
    float* orow = out + ((size_t)b * NS * H + h) * (size_t)W;
    const int c4 = tid & 3;
    const int w4 = tid >> 2;          // 0..79: float4 index in the row
#pragma unroll 1
    for (int s = 0; s < NS; ++s) {
        __syncthreads();   // previous plane's reads / main-loop buffers free
        *reinterpret_cast<float4*>(&bufA[r][4 * q]) =
            make_float4(acc[0][s], acc[1][s], acc[2][s], acc[3][s]);
        __syncthreads();
        if (c4 == (s & 3)) {
            const float4 s0 = *reinterpret_cast<const float4*>(&bufA[0][4 * w4]);
            const float4 s1 = *reinterpret_cast<const float4*>(&bufA[1][4 * w4]);
            const float4 s2 = *reinterpret_cast<const float4*>(&bufA[2][4 * w4]);
            const float4 s3 = *reinterpret_cast<const float4*>(&bufA[3][4 * w4]);
            float4 v;
            v.x = (s0.x + s1.x + s2.x + s3.x) * scale;
            v.y = (s0.y + s1.y + s2.y + s3.y) * scale;
            v.z = (s0.z + s1.z + s2.z + s3.z) * scale;
            v.w = (s0.w + s1.w + s2.w + s3.w) * scale;
            *reinterpret_cast<float4*>(orow + (size_t)s * HW + 4 * w4) = v;
        }
    }
}

extern "C" void kernel_launch(void* const* d_in, const int* in_sizes, int n_in,
                              void* d_out, int out_size, void* d_ws, size_t ws_size,
                              hipStream_t stream) {
    const float* f1 = (const float*)d_in[0];
    const float* f2 = (const float*)d_in[1];
    float* out = (float*)d_out;

    dim3 grid(B * H);    // 768 blocks = 3 per CU
    dim3 block(NTH);     // 320 threads = 5 waves
    hipLaunchKernelGGL(cv_kernel, grid, block, 0, stream, f1, f2, out);
}

// Round 15
// 119.197 us; speedup vs baseline: 1.0325x; 1.0325x over previous
//
#include <hip/hip_runtime.h>

// Cost volume, D=4: out[b,s,h,w] = mean_c feat1[b,c,h,w] * feat2[b,c,h,w+s-4]
// feat1/feat2: (8, 256, 96, 320) f32; out: (8, 9, 96, 320) f32.
// R15: single kernel, NC=1. Block = 4 consecutive h-rows x ALL 256 channels
// (grid 192). R5's PROVEN load geometry: per channel the block reads two
// 5KB-contiguous chunks (4 rows x 1280B). Thread accumulates the full
// channel sum -> direct float4 stores (5KB contiguous per plane per block).
// 2 channels per STEP (128 barriers) + depth-2-pair register prefetch
// (8 loads/thread in flight; ds_write's vmcnt wait satisfied 2 STEPs ago).
// R13/14 lesson: channel-interleaved 1280B chunks cost ~24% demand BW vs
// R5's 5KB chunks; WRITE amplification does NOT respond to store width.
// R11: no deep rotation under tight VGPR budget (watch WRITE for spill).
// R10: no fences / cross-block sync.

constexpr int B  = 8;
constexpr int C  = 256;
constexpr int H  = 96;
constexpr int W  = 320;
constexpr int NS = 9;              // 2*D+1 shifts
constexpr int QT = W / 4;          // 80 float4 per row
constexpr int RPB = 4;             // rows per block
constexpr int NTH = RPB * QT;      // 320 threads: tid = r*80 + q
constexpr int HW  = H * W;
constexpr int PADW = W + 8;        // 4-float zero halo each side
constexpr int NSTEP = C / 2;       // 128 STEPs, 2 channels each

__global__ __launch_bounds__(NTH, 4)
void cv_kernel(const float* __restrict__ f1,
               const float* __restrict__ f2,
               float* __restrict__ out) {
    // 4 channel-slots x 4 rows; slots {0,1} and {2,3} alternate per STEP.
    __shared__ float buf[4][RPB][PADW];   // 21 KB

    const int tid = threadIdx.x;
    const int q   = tid % QT;          // float4 index within the row
    const int r   = tid / QT;          // h-row within block (R5 geometry)

    const int blk = blockIdx.x;        // 192 blocks = 8b x 24 row-groups
    const int hb  = blk % (H / RPB);
    const int b   = blk / (H / RPB);
    const int h   = hb * RPB + r;

    // channel-0 addresses; channel c at +c*HW
    const float* p1 = f1 + ((size_t)b * C * H + (size_t)h) * W + 4 * q;
    const float* p2 = f2 + ((size_t)b * C * H + (size_t)h) * W + 4 * q;

    // Zero halo pads of all 4 slots once (covered by first STEP's barrier).
    if (q == 0) {
#pragma unroll
        for (int p = 0; p < 4; ++p)
#pragma unroll
            for (int k = 0; k < 4; ++k) buf[p][r][k] = 0.f;
    }
    if (q == QT - 1) {
#pragma unroll
        for (int p = 0; p < 4; ++p)
#pragma unroll
            for (int k = 0; k < 4; ++k) buf[p][r][4 + W + k] = 0.f;
    }

    float acc[4][NS];
#pragma unroll
    for (int j = 0; j < 4; ++j)
#pragma unroll
        for (int s = 0; s < NS; ++s) acc[j][s] = 0.0f;

    // Prologue: channels 0..3 in registers (two pairs in flight).
    float4 a0 = *reinterpret_cast<const float4*>(p1);
    float4 r0 = *reinterpret_cast<const float4*>(p2);
    float4 a1 = *reinterpret_cast<const float4*>(p1 + (size_t)HW);
    float4 r1 = *reinterpret_cast<const float4*>(p2 + (size_t)HW);
    float4 a2 = *reinterpret_cast<const float4*>(p1 + 2 * (size_t)HW);
    float4 r2 = *reinterpret_cast<const float4*>(p2 + 2 * (size_t)HW);
    float4 a3 = *reinterpret_cast<const float4*>(p1 + 3 * (size_t)HW);
    float4 r3 = *reinterpret_cast<const float4*>(p2 + 3 * (size_t)HW);
    int cL = 4;   // next channel to issue; clamped at C-2 (dummy hot reload)

    // STEP: channels (a0,r0),(a1,r1) -> LDS slots P0,P1; prefetch pair cL.
    //   ds_write both feat2 rows (their loads landed >=2 STEPs ago -> no
    //   vmcnt stall) -> issue 4 loads -> lgkmcnt(0) + raw s_barrier
    //   (prefetch loads stay in flight across it) -> two unconditional
    //   12-float windows from padded LDS (middle 4 from register) ->
    //   72 FMAs -> rotate pairs.
#define CV_FMA(AV, X0, RM, X2)                                             \
    {                                                                      \
        const float xw[12] = {X0.x, X0.y, X0.z, X0.w,                      \
                              RM.x, RM.y, RM.z, RM.w,                      \
                              X2.x, X2.y, X2.z, X2.w};                     \
        const float av[4] = {AV.x, AV.y, AV.z, AV.w};                      \
        _Pragma("unroll")                                                  \
        for (int j = 0; j < 4; ++j)                                        \
            _Pragma("unroll")                                              \
            for (int s = 0; s < NS; ++s)                                   \
                acc[j][s] = fmaf(av[j], xw[j + s], acc[j][s]);             \
    }

#define STEP(P0, P1)                                                       \
    {                                                                      \
        *reinterpret_cast<float4*>(&buf[P0][r][4 + 4 * q]) = r0;           \
        *reinterpret_cast<float4*>(&buf[P1][r][4 + 4 * q]) = r1;           \
        const float4 aL0 = *reinterpret_cast<const float4*>(               \
            p1 + (size_t)cL * HW);                                         \
        const float4 rL0 = *reinterpret_cast<const float4*>(               \
            p2 + (size_t)cL * HW);                                         \
        const float4 aL1 = *reinterpret_cast<const float4*>(               \
            p1 + (size_t)(cL + 1) * HW);                                   \
        const float4 rL1 = *reinterpret_cast<const float4*>(               \
            p2 + (size_t)(cL + 1) * HW);                                   \
        cL = (cL < C - 2) ? cL + 2 : cL;                                   \
        asm volatile("s_waitcnt lgkmcnt(0)" ::: "memory");                 \
        __builtin_amdgcn_s_barrier();                                      \
        asm volatile("" ::: "memory");                                     \
        const float4 x0a =                                                 \
            *reinterpret_cast<const float4*>(&buf[P0][r][4 * q]);          \
        const float4 x2a =                                                 \
            *reinterpret_cast<const float4*>(&buf[P0][r][4 * q + 8]);      \
        const float4 x0b =                                                 \
            *reinterpret_cast<const float4*>(&buf[P1][r][4 * q]);          \
        const float4 x2b =                                                 \
            *reinterpret_cast<const float4*>(&buf[P1][r][4 * q + 8]);      \
        CV_FMA(a0, x0a, r0, x2a)                                           \
        CV_FMA(a1, x0b, r1, x2b)                                           \
        a0 = a2; r0 = r2; a1 = a3; r1 = r3;                                \
        a2 = aL0; r2 = rL0; a3 = aL1; r3 = rL1;                            \
    }

#pragma unroll 1
    for (int s = 0; s < NSTEP; s += 2) {
        STEP(0, 1)
        STEP(2, 3)
    }
#undef STEP
#undef CV_FMA

    // Epilogue: direct output. Thread owns the full channel sum of its
    // (h, 4q..4q+3) -> 9 float4 stores; per plane per block 4 consecutive
    // h-rows x 1280B = 5120B contiguous (R5's proven exact-write pattern).
    const float scale = 1.0f / (float)C;
    float* obase = out + (((size_t)b * NS) * H + h) * (size_t)W + 4 * q;
#pragma unroll
    for (int s = 0; s < NS; ++s) {
        float4 v = make_float4(acc[0][s] * scale, acc[1][s] * scale,
                               acc[2][s] * scale, acc[3][s] * scale);
        *reinterpret_cast<float4*>(obase + (size_t)s * HW) = v;
    }
}

extern "C" void kernel_launch(void* const* d_in, const int* in_sizes, int n_in,
                              void* d_out, int out_size, void* d_ws, size_t ws_size,
                              hipStream_t stream) {
    const float* f1 = (const float*)d_in[0];
    const float* f2 = (const float*)d_in[1];
    float* out = (float*)d_out;

    dim3 grid(B * (H / RPB));   // 192 blocks
    dim3 block(NTH);            // 320 threads = 5 waves
    hipLaunchKernelGGL(cv_kernel, grid, block, 0, stream, f1, f2, out);
}

// Round 16
// 97.209 us; speedup vs baseline: 1.2661x; 1.2262x over previous
//
#include <hip/hip_runtime.h>

// Cost volume, D=4: out[b,s,h,w] = mean_c feat1[b,c,h,w] * feat2[b,c,h,w+s-4]
// feat1/feat2: (8, 256, 96, 320) f32; out: (8, 9, 96, 320) f32.
// R16 = R15 skeleton (block = 4 h-rows x all 256 channels, grid 192, 5KB
// contiguous loads AND stores, 2 channels/STEP, padded-LDS feat2 windows,
// lgkmcnt(0)+raw-barrier pinning) + depth-3-pair register prefetch (12
// float4/thread in flight, issue->use = 3 STEPs) under __launch_bounds__(,1)
// (~256 VGPR budget: no R4-collapse, no R11-spill).
// R15 lesson: write amplification tracks per-block output contiguity
// (5KB/plane exact; 1.25KB -> 6.8x), not store width. Occupancy 10% ->
// the stall is issue-to-use distance, there is no TLP to hide it.
// R10: no fences/cross-block sync.

constexpr int B  = 8;
constexpr int C  = 256;
constexpr int H  = 96;
constexpr int W  = 320;
constexpr int NS = 9;              // 2*D+1 shifts
constexpr int QT = W / 4;          // 80 float4 per row
constexpr int RPB = 4;             // rows per block
constexpr int NTH = RPB * QT;      // 320 threads: tid = r*80 + q
constexpr int HW  = H * W;
constexpr int PADW = W + 8;        // 4-float zero halo each side
constexpr int NSTEP = C / 2;       // 128 STEPs, 2 channels each

__global__ __launch_bounds__(NTH, 1)
void cv_kernel(const float* __restrict__ f1,
               const float* __restrict__ f2,
               float* __restrict__ out) {
    // 4 channel-slots x 4 rows; slots {0,1} and {2,3} alternate per STEP.
    __shared__ float buf[4][RPB][PADW];   // 21 KB

    const int tid = threadIdx.x;
    const int q   = tid % QT;          // float4 index within the row
    const int r   = tid / QT;          // h-row within block

    const int blk = blockIdx.x;        // 192 blocks = 8b x 24 row-groups
    const int hb  = blk % (H / RPB);
    const int b   = blk / (H / RPB);
    const int h   = hb * RPB + r;

    // channel-0 addresses; channel c at +c*HW
    const float* p1 = f1 + ((size_t)b * C * H + (size_t)h) * W + 4 * q;
    const float* p2 = f2 + ((size_t)b * C * H + (size_t)h) * W + 4 * q;

    // Zero halo pads of all 4 slots once (covered by first STEP's barrier).
    if (q == 0) {
#pragma unroll
        for (int p = 0; p < 4; ++p)
#pragma unroll
            for (int k = 0; k < 4; ++k) buf[p][r][k] = 0.f;
    }
    if (q == QT - 1) {
#pragma unroll
        for (int p = 0; p < 4; ++p)
#pragma unroll
            for (int k = 0; k < 4; ++k) buf[p][r][4 + W + k] = 0.f;
    }

    float acc[4][NS];
#pragma unroll
    for (int j = 0; j < 4; ++j)
#pragma unroll
        for (int s = 0; s < NS; ++s) acc[j][s] = 0.0f;

    // Prologue: channels 0..5 in registers (three pairs in flight).
    float4 a0 = *reinterpret_cast<const float4*>(p1);
    float4 r0 = *reinterpret_cast<const float4*>(p2);
    float4 a1 = *reinterpret_cast<const float4*>(p1 + (size_t)HW);
    float4 r1 = *reinterpret_cast<const float4*>(p2 + (size_t)HW);
    float4 a2 = *reinterpret_cast<const float4*>(p1 + 2 * (size_t)HW);
    float4 r2 = *reinterpret_cast<const float4*>(p2 + 2 * (size_t)HW);
    float4 a3 = *reinterpret_cast<const float4*>(p1 + 3 * (size_t)HW);
    float4 r3 = *reinterpret_cast<const float4*>(p2 + 3 * (size_t)HW);
    float4 a4 = *reinterpret_cast<const float4*>(p1 + 4 * (size_t)HW);
    float4 r4 = *reinterpret_cast<const float4*>(p2 + 4 * (size_t)HW);
    float4 a5 = *reinterpret_cast<const float4*>(p1 + 5 * (size_t)HW);
    float4 r5 = *reinterpret_cast<const float4*>(p2 + 5 * (size_t)HW);
    int cL = 6;   // next channel to issue; clamped at C-2 (dummy hot reload)

    // STEP: consume channels (a0,r0),(a1,r1) via LDS slots P0,P1; issue the
    // pair cL,cL+1 (lands 3 STEPs from now). ds_write's implicit vmcnt wait
    // targets loads issued 3 STEPs ago -> long since landed.
#define CV_FMA(AV, X0, RM, X2)                                             \
    {                                                                      \
        const float xw[12] = {X0.x, X0.y, X0.z, X0.w,                      \
                              RM.x, RM.y, RM.z, RM.w,                      \
                              X2.x, X2.y, X2.z, X2.w};                     \
        const float av[4] = {AV.x, AV.y, AV.z, AV.w};                      \
        _Pragma("unroll")                                                  \
        for (int j = 0; j < 4; ++j)                                        \
            _Pragma("unroll")                                              \
            for (int s = 0; s < NS; ++s)                                   \
                acc[j][s] = fmaf(av[j], xw[j + s], acc[j][s]);             \
    }

#define STEP(P0, P1)                                                       \
    {                                                                      \
        *reinterpret_cast<float4*>(&buf[P0][r][4 + 4 * q]) = r0;           \
        *reinterpret_cast<float4*>(&buf[P1][r][4 + 4 * q]) = r1;           \
        const float4 aL0 = *reinterpret_cast<const float4*>(               \
            p1 + (size_t)cL * HW);                                         \
        const float4 rL0 = *reinterpret_cast<const float4*>(               \
            p2 + (size_t)cL * HW);                                         \
        const float4 aL1 = *reinterpret_cast<const float4*>(               \
            p1 + (size_t)(cL + 1) * HW);                                   \
        const float4 rL1 = *reinterpret_cast<const float4*>(               \
            p2 + (size_t)(cL + 1) * HW);                                   \
        cL = (cL < C - 2) ? cL + 2 : cL;                                   \
        asm volatile("s_waitcnt lgkmcnt(0)" ::: "memory");                 \
        __builtin_amdgcn_s_barrier();                                      \
        asm volatile("" ::: "memory");                                     \
        const float4 x0a =                                                 \
            *reinterpret_cast<const float4*>(&buf[P0][r][4 * q]);          \
        const float4 x2a =                                                 \
            *reinterpret_cast<const float4*>(&buf[P0][r][4 * q + 8]);      \
        const float4 x0b =                                                 \
            *reinterpret_cast<const float4*>(&buf[P1][r][4 * q]);          \
        const float4 x2b =                                                 \
            *reinterpret_cast<const float4*>(&buf[P1][r][4 * q + 8]);      \
        CV_FMA(a0, x0a, r0, x2a)                                           \
        CV_FMA(a1, x0b, r1, x2b)                                           \
        a0 = a2; r0 = r2; a1 = a3; r1 = r3;                                \
        a2 = a4; r2 = r4; a3 = a5; r3 = r5;                                \
        a4 = aL0; r4 = rL0; a5 = aL1; r5 = rL1;                            \
    }

#pragma unroll 1
    for (int s = 0; s < NSTEP; s += 2) {
        STEP(0, 1)
        STEP(2, 3)
    }
#undef STEP
#undef CV_FMA

    // Epilogue: direct output. Thread owns the full channel sum of its
    // (h, 4q..4q+3) -> 9 float4 stores; per plane per block 4 consecutive
    // h-rows x 1280B = 5120B contiguous (exact-write pattern, R15-proven).
    const float scale = 1.0f / (float)C;
    float* obase = out + (((size_t)b * NS) * H + h) * (size_t)W + 4 * q;
#pragma unroll
    for (int s = 0; s < NS; ++s) {
        float4 v = make_float4(acc[0][s] * scale, acc[1][s] * scale,
                               acc[2][s] * scale, acc[3][s] * scale);
        *reinterpret_cast<float4*>(obase + (size_t)s * HW) = v;
    }
}

extern "C" void kernel_launch(void* const* d_in, const int* in_sizes, int n_in,
                              void* d_out, int out_size, void* d_ws, size_t ws_size,
                              hipStream_t stream) {
    const float* f1 = (const float*)d_in[0];
    const float* f2 = (const float*)d_in[1];
    float* out = (float*)d_out;

    dim3 grid(B * (H / RPB));   // 192 blocks
    dim3 block(NTH);            // 320 threads = 5 waves
    hipLaunchKernelGGL(cv_kernel, grid, block, 0, stream, f1, f2, out);
}

// Round 17
// 92.783 us; speedup vs baseline: 1.3264x; 1.0477x over previous
//
#include <hip/hip_runtime.h>

// Cost volume, D=4: out[b,s,h,w] = mean_c feat1[b,c,h,w] * feat2[b,c,h,w+s-4]
// feat1/feat2: (8, 256, 96, 320) f32; out: (8, 9, 96, 320) f32.
// R17 = R16 structure (depth-3-pair register prefetch, 2 channels/STEP,
// padded-LDS feat2 windows, lgkmcnt(0)+raw-barrier pinning, direct float4
// epilogue) with RPB 4 -> 3: grid 192 -> 256 blocks fills ALL 256 CUs.
// R16 counters: per-busy-CU demand rate (27.4 GB/s) already exceeds the
// copy-ceiling per-CU average (24.6) -> grid shape, not the pipeline, is
// the limiter. 240-thread blocks (3.75 waves) cost 6.25% lane waste only.
// Per-block contiguity: 3840B loads/channel, 3840B stores/plane (tests the
// write-amplification threshold; 5KB exact, 1.25KB -> 6.8x).
// R11: watch WRITE_SIZE for spill/amplification. R10: no fences.

constexpr int B  = 8;
constexpr int C  = 256;
constexpr int H  = 96;
constexpr int W  = 320;
constexpr int NS = 9;              // 2*D+1 shifts
constexpr int QT = W / 4;          // 80 float4 per row
constexpr int RPB = 3;             // rows per block -> 256 blocks
constexpr int NTH = RPB * QT;      // 240 threads: tid = r*80 + q
constexpr int HW  = H * W;
constexpr int PADW = W + 8;        // 4-float zero halo each side
constexpr int NSTEP = C / 2;       // 128 STEPs, 2 channels each

__global__ __launch_bounds__(NTH, 1)
void cv_kernel(const float* __restrict__ f1,
               const float* __restrict__ f2,
               float* __restrict__ out) {
    // 4 channel-slots x 3 rows; slots {0,1} and {2,3} alternate per STEP.
    __shared__ float buf[4][RPB][PADW];   // 15.7 KB

    const int tid = threadIdx.x;
    const int q   = tid % QT;          // float4 index within the row
    const int r   = tid / QT;          // h-row within block (0..2)

    const int blk = blockIdx.x;        // 256 blocks = 8b x 32 row-groups
    const int hb  = blk % (H / RPB);
    const int b   = blk / (H / RPB);
    const int h   = hb * RPB + r;

    // channel-0 addresses; channel c at +c*HW
    const float* p1 = f1 + ((size_t)b * C * H + (size_t)h) * W + 4 * q;
    const float* p2 = f2 + ((size_t)b * C * H + (size_t)h) * W + 4 * q;

    // Zero halo pads of all 4 slots once (covered by first STEP's barrier).
    if (q == 0) {
#pragma unroll
        for (int p = 0; p < 4; ++p)
#pragma unroll
            for (int k = 0; k < 4; ++k) buf[p][r][k] = 0.f;
    }
    if (q == QT - 1) {
#pragma unroll
        for (int p = 0; p < 4; ++p)
#pragma unroll
            for (int k = 0; k < 4; ++k) buf[p][r][4 + W + k] = 0.f;
    }

    float acc[4][NS];
#pragma unroll
    for (int j = 0; j < 4; ++j)
#pragma unroll
        for (int s = 0; s < NS; ++s) acc[j][s] = 0.0f;

    // Prologue: channels 0..5 in registers (three pairs in flight).
    float4 a0 = *reinterpret_cast<const float4*>(p1);
    float4 r0 = *reinterpret_cast<const float4*>(p2);
    float4 a1 = *reinterpret_cast<const float4*>(p1 + (size_t)HW);
    float4 r1 = *reinterpret_cast<const float4*>(p2 + (size_t)HW);
    float4 a2 = *reinterpret_cast<const float4*>(p1 + 2 * (size_t)HW);
    float4 r2 = *reinterpret_cast<const float4*>(p2 + 2 * (size_t)HW);
    float4 a3 = *reinterpret_cast<const float4*>(p1 + 3 * (size_t)HW);
    float4 r3 = *reinterpret_cast<const float4*>(p2 + 3 * (size_t)HW);
    float4 a4 = *reinterpret_cast<const float4*>(p1 + 4 * (size_t)HW);
    float4 r4 = *reinterpret_cast<const float4*>(p2 + 4 * (size_t)HW);
    float4 a5 = *reinterpret_cast<const float4*>(p1 + 5 * (size_t)HW);
    float4 r5 = *reinterpret_cast<const float4*>(p2 + 5 * (size_t)HW);
    int cL = 6;   // next channel to issue; clamped at C-2 (dummy hot reload)

    // STEP: consume channels (a0,r0),(a1,r1) via LDS slots P0,P1; issue the
    // pair cL,cL+1 (lands 3 STEPs from now). ds_write's implicit vmcnt wait
    // targets loads issued 3 STEPs ago -> long since landed.
#define CV_FMA(AV, X0, RM, X2)                                             \
    {                                                                      \
        const float xw[12] = {X0.x, X0.y, X0.z, X0.w,                      \
                              RM.x, RM.y, RM.z, RM.w,                      \
                              X2.x, X2.y, X2.z, X2.w};                     \
        const float av[4] = {AV.x, AV.y, AV.z, AV.w};                      \
        _Pragma("unroll")                                                  \
        for (int j = 0; j < 4; ++j)                                        \
            _Pragma("unroll")                                              \
            for (int s = 0; s < NS; ++s)                                   \
                acc[j][s] = fmaf(av[j], xw[j + s], acc[j][s]);             \
    }

#define STEP(P0, P1)                                                       \
    {                                                                      \
        *reinterpret_cast<float4*>(&buf[P0][r][4 + 4 * q]) = r0;           \
        *reinterpret_cast<float4*>(&buf[P1][r][4 + 4 * q]) = r1;           \
        const float4 aL0 = *reinterpret_cast<const float4*>(               \
            p1 + (size_t)cL * HW);                                         \
        const float4 rL0 = *reinterpret_cast<const float4*>(               \
            p2 + (size_t)cL * HW);                                         \
        const float4 aL1 = *reinterpret_cast<const float4*>(               \
            p1 + (size_t)(cL + 1) * HW);                                   \
        const float4 rL1 = *reinterpret_cast<const float4*>(               \
            p2 + (size_t)(cL + 1) * HW);                                   \
        cL = (cL < C - 2) ? cL + 2 : cL;                                   \
        asm volatile("s_waitcnt lgkmcnt(0)" ::: "memory");                 \
        __builtin_amdgcn_s_barrier();                                      \
        asm volatile("" ::: "memory");                                     \
        const float4 x0a =                                                 \
            *reinterpret_cast<const float4*>(&buf[P0][r][4 * q]);          \
        const float4 x2a =                                                 \
            *reinterpret_cast<const float4*>(&buf[P0][r][4 * q + 8]);      \
        const float4 x0b =                                                 \
            *reinterpret_cast<const float4*>(&buf[P1][r][4 * q]);          \
        const float4 x2b =                                                 \
            *reinterpret_cast<const float4*>(&buf[P1][r][4 * q + 8]);      \
        CV_FMA(a0, x0a, r0, x2a)                                           \
        CV_FMA(a1, x0b, r1, x2b)                                           \
        a0 = a2; r0 = r2; a1 = a3; r1 = r3;                                \
        a2 = a4; r2 = r4; a3 = a5; r3 = r5;                                \
        a4 = aL0; r4 = rL0; a5 = aL1; r5 = rL1;                            \
    }

#pragma unroll 1
    for (int s = 0; s < NSTEP; s += 2) {
        STEP(0, 1)
        STEP(2, 3)
    }
#undef STEP
#undef CV_FMA

    // Epilogue: direct output. Thread owns the full channel sum of its
    // (h, 4q..4q+3) -> 9 float4 stores; per plane per block 3 consecutive
    // h-rows x 1280B = 3840B contiguous.
    const float scale = 1.0f / (float)C;
    float* obase = out + (((size_t)b * NS) * H + h) * (size_t)W + 4 * q;
#pragma unroll
    for (int s = 0; s < NS; ++s) {
        float4 v = make_float4(acc[0][s] * scale, acc[1][s] * scale,
                               acc[2][s] * scale, acc[3][s] * scale);
        *reinterpret_cast<float4*>(obase + (size_t)s * HW) = v;
    }
}

extern "C" void kernel_launch(void* const* d_in, const int* in_sizes, int n_in,
                              void* d_out, int out_size, void* d_ws, size_t ws_size,
                              hipStream_t stream) {
    const float* f1 = (const float*)d_in[0];
    const float* f2 = (const float*)d_in[1];
    float* out = (float*)d_out;

    dim3 grid(B * (H / RPB));   // 256 blocks = 1 per CU
    dim3 block(NTH);            // 240 threads = 3.75 waves
    hipLaunchKernelGGL(cv_kernel, grid, block, 0, stream, f1, f2, out);
}